// Round 2
// baseline (2129.442 us; speedup 1.0000x reference)
//
#include <hip/hip_runtime.h>

#define BB 8
#define SS 512
#define DD 512
#define NH 8
#define DHm 256
#define DEP 32
#define DFF 2048

// ---------------- generic tiled GEMM: C = act(A @ op(B) + bias) ----------------
// A: (M,K) lda ; B: (K,N) ldb, or TRANSB -> B:(N,K) ldb ; C: (M,N) ldc fp32.
// Batched over blockIdx.z with element strides sA,sB,sC. ACT: 0=none,1=relu,2=gelu(erf)
template<bool TRANSB, int ACT>
__global__ __launch_bounds__(256)
void gemm_kernel(const float* __restrict__ A, const float* __restrict__ B,
                 const float* __restrict__ bias, float* __restrict__ C,
                 int M, int N, int K, int lda, int ldb, int ldc,
                 long long sA, long long sB, long long sC)
{
  __shared__ float As[32][33];
  __shared__ float Bs[32][33];
  const int tx = threadIdx.x, ty = threadIdx.y;
  const int t = ty*16 + tx;
  const int row0 = blockIdx.y*32, col0 = blockIdx.x*32;
  const float* Ab = A + (long long)blockIdx.z * sA;
  const float* Bb = B + (long long)blockIdx.z * sB;
  float* Cb = C + (long long)blockIdx.z * sC;
  float acc00=0.f, acc01=0.f, acc10=0.f, acc11=0.f;
  for (int k0=0; k0<K; k0+=32) {
#pragma unroll
    for (int i=0;i<4;i++) {
      int idx = t + i*256;
      int r = idx>>5, c = idx&31;
      {
        int gr = row0+r, gc = k0+c;
        As[r][c] = (gr<M && gc<K) ? Ab[(long long)gr*lda + gc] : 0.f;
      }
      if (TRANSB) {
        int kk = idx&31, nn = idx>>5;
        int gk = k0+kk, gn = col0+nn;
        Bs[kk][nn] = (gn<N && gk<K) ? Bb[(long long)gn*ldb + gk] : 0.f;
      } else {
        int gk = k0+r, gn = col0+c;
        Bs[r][c] = (gk<K && gn<N) ? Bb[(long long)gk*ldb + gn] : 0.f;
      }
    }
    __syncthreads();
#pragma unroll
    for (int kk=0;kk<32;kk++) {
      float a0 = As[ty*2+0][kk], a1 = As[ty*2+1][kk];
      float b0 = Bs[kk][tx*2+0], b1 = Bs[kk][tx*2+1];
      acc00 += a0*b0; acc01 += a0*b1;
      acc10 += a1*b0; acc11 += a1*b1;
    }
    __syncthreads();
  }
  float accs[2][2] = {{acc00,acc01},{acc10,acc11}};
#pragma unroll
  for (int i=0;i<2;i++) {
#pragma unroll
    for (int j=0;j<2;j++) {
      int r = row0 + ty*2 + i, c = col0 + tx*2 + j;
      if (r<M && c<N) {
        float v = accs[i][j];
        if (bias) v += bias[c];
        if (ACT==1) v = fmaxf(v, 0.f);
        if (ACT==2) v = 0.5f*v*(1.f + erff(v*0.70710678118654752f));
        Cb[(long long)r*ldc + c] = v;
      }
    }
  }
}

// ---------------- attention: one block per (b,h,q) ----------------
// BRANCH 1: scores/scale + mask*(-1e9) + adjoin
// BRANCH 2: relu(scores)*rescale(dist)/scale + mask*(-1e9)
template<int BRANCH>
__global__ __launch_bounds__(256)
void attn_kernel(const float* __restrict__ Q, const float* __restrict__ K,
                 const float* __restrict__ V, const int* __restrict__ mask,
                 const float* __restrict__ extra, float* __restrict__ aw,
                 float* __restrict__ ctx)
{
  const int q = blockIdx.x, h = blockIdx.y, b = blockIdx.z;
  const int t = threadIdx.x;
  __shared__ float qv[DEP];
  __shared__ float sc[SS];
  __shared__ float red[256];
  if (t < DEP) qv[t] = Q[((long long)(b*SS+q))*DHm + h*DEP + t];
  __syncthreads();
  const float scale_inv = 0.17677669529663688f; // 1/sqrt(32)
  for (int k=t; k<SS; k+=256) {
    const float* kr = K + ((long long)(b*SS+k))*DHm + h*DEP;
    float s = 0.f;
#pragma unroll
    for (int d=0; d<DEP; d++) s += qv[d]*kr[d];
    float m = (float)mask[b*SS + k];
    float ev = extra[((long long)b*SS + q)*SS + k];
    if (BRANCH==1) {
      s = s*scale_inv + m*(-1e9f) + ev;
    } else {
      float resc = 3.7182818284590452f / (1.f + expf(1.f - ev)); // (1+e)/(1+exp(1-w))
      s = fmaxf(s, 0.f)*resc*scale_inv + m*(-1e9f);
    }
    sc[k] = s;
  }
  __syncthreads();
  float l0 = sc[t], l1 = sc[t+256];
  red[t] = fmaxf(l0, l1);
  __syncthreads();
  for (int o=128;o>0;o>>=1) { if (t<o) red[t] = fmaxf(red[t], red[t+o]); __syncthreads(); }
  float mx = red[0];
  __syncthreads();
  float e0 = expf(l0-mx), e1 = expf(l1-mx);
  red[t] = e0 + e1;
  __syncthreads();
  for (int o=128;o>0;o>>=1) { if (t<o) red[t] += red[t+o]; __syncthreads(); }
  float inv = 1.f/red[0];
  float p0 = e0*inv, p1 = e1*inv;
  sc[t] = p0; sc[t+256] = p1;
  long long awb = (((long long)b*NH + h)*SS + q)*SS;
  aw[awb + t]       = p0;
  aw[awb + t + 256] = p1;
  __syncthreads();
  // ctx[d] = sum_k p[k]*V[k][d]; 8 partials of 64 k's per dim
  int d = t & (DEP-1), part = t >> 5;
  float ps = 0.f;
  int k0 = part*64;
  for (int k=k0; k<k0+64; k++) ps += sc[k] * V[((long long)(b*SS+k))*DHm + h*DEP + d];
  red[t] = ps;
  __syncthreads();
  if (t < DEP) {
    float s2 = 0.f;
#pragma unroll
    for (int p=0;p<8;p++) s2 += red[p*32 + t];
    ctx[((long long)(b*SS+q))*DHm + h*DEP + t] = s2;
  }
}

// ---------------- vh = v_ * (h_mat[0,:]+h_mat[1,:]) ----------------
__global__ __launch_bounds__(256)
void vh_kernel(const float* __restrict__ v_, const float* __restrict__ hmat,
               float* __restrict__ vh, int n)
{
  int i = blockIdx.x*256 + threadIdx.x;
  if (i < n) {
    int c = i & (DD-1);
    vh[i] = v_[i] * (hmat[c] + hmat[DD + c]);
  }
}

// ---------------- G += h_bias[0]+h_bias[1] ----------------
__global__ __launch_bounds__(256)
void addhb_kernel(float* __restrict__ G, const float* __restrict__ hb, int n)
{
  int i = blockIdx.x*256 + threadIdx.x;
  if (i < n) G[i] += hb[0] + hb[1];
}

// ---------------- BN(eval) + gate + residual + LN1 (one block per row) ----------------
__global__ __launch_bounds__(256)
void bn_gate_ln1_kernel(const float* __restrict__ x, const float* __restrict__ vbuf,
                        const float* __restrict__ T, const float* __restrict__ xl,
                        const float* __restrict__ xg,
                        const float* __restrict__ bng, const float* __restrict__ bnb,
                        const float* __restrict__ bnm, const float* __restrict__ bnv,
                        const float* __restrict__ lng, const float* __restrict__ lnb,
                        float* __restrict__ out1)
{
  const int row = blockIdx.x;
  const int t = threadIdx.x;
  __shared__ float red[256];
  float val[2];
#pragma unroll
  for (int i=0;i<2;i++) {
    int c = t + i*256;
    long long idx = (long long)row*DD + c;
    float lg = vbuf[idx]*T[idx];
    float bn = (lg - bnm[c]) / sqrtf(bnv[c] + 1e-3f) * bng[c] + bnb[c];
    float gate = (c < DHm) ? xl[(long long)row*DHm + c] : xg[(long long)row*DHm + (c-DHm)];
    val[i] = x[idx] + bn*gate;
  }
  red[t] = val[0] + val[1];
  __syncthreads();
  for (int o=128;o>0;o>>=1) { if (t<o) red[t]+=red[t+o]; __syncthreads(); }
  float mu = red[0] * (1.f/512.f);
  __syncthreads();
  float d0 = val[0]-mu, d1 = val[1]-mu;
  red[t] = d0*d0 + d1*d1;
  __syncthreads();
  for (int o=128;o>0;o>>=1) { if (t<o) red[t]+=red[t+o]; __syncthreads(); }
  float inv = 1.f / sqrtf(red[0]*(1.f/512.f) + 1e-6f);
  out1[(long long)row*DD + t]       = d0*inv*lng[t]     + lnb[t];
  out1[(long long)row*DD + t + 256] = d1*inv*lng[t+256] + lnb[t+256];
}

// ---------------- residual + LN2 -> out ----------------
__global__ __launch_bounds__(256)
void ln2_kernel(const float* __restrict__ a, const float* __restrict__ b2,
                const float* __restrict__ g, const float* __restrict__ bta,
                float* __restrict__ out)
{
  const int row = blockIdx.x;
  const int t = threadIdx.x;
  __shared__ float red[256];
  float v0 = a[(long long)row*DD + t]       + b2[(long long)row*DD + t];
  float v1 = a[(long long)row*DD + t + 256] + b2[(long long)row*DD + t + 256];
  red[t] = v0 + v1;
  __syncthreads();
  for (int o=128;o>0;o>>=1) { if (t<o) red[t]+=red[t+o]; __syncthreads(); }
  float mu = red[0] * (1.f/512.f);
  __syncthreads();
  float d0 = v0-mu, d1 = v1-mu;
  red[t] = d0*d0 + d1*d1;
  __syncthreads();
  for (int o=128;o>0;o>>=1) { if (t<o) red[t]+=red[t+o]; __syncthreads(); }
  float inv = 1.f / sqrtf(red[0]*(1.f/512.f) + 1e-6f);
  out[(long long)row*DD + t]       = d0*inv*g[t]     + bta[t];
  out[(long long)row*DD + t + 256] = d1*inv*g[t+256] + bta[t+256];
}

extern "C" void kernel_launch(void* const* d_in, const int* in_sizes, int n_in,
                              void* d_out, int out_size, void* d_ws, size_t ws_size,
                              hipStream_t stream) {
  const float* x      = (const float*)d_in[0];
  const float* adjoin = (const float*)d_in[1];
  const float* dist   = (const float*)d_in[2];
  const float* wq1=(const float*)d_in[3],  *bq1=(const float*)d_in[4];
  const float* wk1=(const float*)d_in[5],  *bk1=(const float*)d_in[6];
  const float* wv1=(const float*)d_in[7],  *bv1=(const float*)d_in[8];
  const float* wo1=(const float*)d_in[9],  *bo1=(const float*)d_in[10];
  const float* wq2=(const float*)d_in[11], *bq2=(const float*)d_in[12];
  const float* wk2=(const float*)d_in[13], *bk2=(const float*)d_in[14];
  const float* wv2=(const float*)d_in[15], *bv2=(const float*)d_in[16];
  const float* wo2=(const float*)d_in[17], *bo2=(const float*)d_in[18];
  const float* vnet_w=(const float*)d_in[19], *vnet_b=(const float*)d_in[20];
  const float* qnet_w=(const float*)d_in[21], *qnet_b=(const float*)d_in[22];
  const float* h_mat=(const float*)d_in[23], *h_bias=(const float*)d_in[24];
  const float* bn_g=(const float*)d_in[25], *bn_b=(const float*)d_in[26];
  const float* bn_m=(const float*)d_in[27], *bn_v=(const float*)d_in[28];
  const float* ln1_g=(const float*)d_in[29], *ln1_b=(const float*)d_in[30];
  const float* ln2_g=(const float*)d_in[31], *ln2_b=(const float*)d_in[32];
  const float* ffn_w1=(const float*)d_in[33], *ffn_b1=(const float*)d_in[34];
  const float* ffn_w2=(const float*)d_in[35], *ffn_b2=(const float*)d_in[36];
  const int* mask = (const int*)d_in[37];

  float* ws = (float*)d_ws;
  const long long M1 = 1048576LL; // 1M floats
  // compact overlay, peak 12*M1 floats = 48 MB
  float* Qb   = ws + 0*M1;   // (4096,256)          phase 1-2
  float* Kb   = ws + 1*M1;
  float* Vb   = ws + 2*M1;
  float* CTX  = ws + 3*M1;   // (4096,256)
  float* XL   = ws + 4*M1;   // (4096,256)          live until bn_gate
  float* XG   = ws + 5*M1;
  float* Vn   = ws + 6*M1;   // v_ (4096,512) 6-8   live until bn_gate
  float* Qn   = ws + 8*M1;   // q_ (4096,512) 8-10  live until T gemm
  float* VH   = ws + 0*M1;   // (4096,512)   0-2    overlays Qb/Kb (dead)
  float* G    = ws + 2*M1;   // (8,512,512)  2-4    overlays Vb/CTX (dead)
  float* T    = ws + 10*M1;  // (4096,512)  10-12
  float* OUT1 = ws + 0*M1;   // (4096,512)   0-2    overlays VH (dead)
  float* H    = ws + 2*M1;   // (4096,2048)  2-10   overlays G/XL/XG/Vn/Qn (dead)
  float* FFNO = ws + 10*M1;  // (4096,512)  10-12   overlays T (dead)

  float* out2 = (float*)d_out;
  float* awl  = out2 + 2097152LL;
  float* awg  = awl + 16777216LL;

  const int MROWS = BB*SS; // 4096
  dim3 blk(16,16);
  const long long GST = (long long)SS*SS; // 262144

  // ---- branch 1 (local / adjoin) ----
  gemm_kernel<false,0><<<dim3(DHm/32, MROWS/32, 1), blk, 0, stream>>>(
      x,       wq1, bq1, Qb, MROWS, DHm, DHm, DD, DHm, DHm, 0,0,0);
  gemm_kernel<false,0><<<dim3(DHm/32, MROWS/32, 1), blk, 0, stream>>>(
      x,       wk1, bk1, Kb, MROWS, DHm, DHm, DD, DHm, DHm, 0,0,0);
  gemm_kernel<false,0><<<dim3(DHm/32, MROWS/32, 1), blk, 0, stream>>>(
      x,       wv1, bv1, Vb, MROWS, DHm, DHm, DD, DHm, DHm, 0,0,0);
  attn_kernel<1><<<dim3(SS, NH, BB), 256, 0, stream>>>(Qb, Kb, Vb, mask, adjoin, awl, CTX);
  gemm_kernel<false,0><<<dim3(DHm/32, MROWS/32, 1), blk, 0, stream>>>(
      CTX, wo1, bo1, XL, MROWS, DHm, DHm, DHm, DHm, DHm, 0,0,0);

  // ---- branch 2 (global / distance) ----
  gemm_kernel<false,0><<<dim3(DHm/32, MROWS/32, 1), blk, 0, stream>>>(
      x+DHm,   wq2, bq2, Qb, MROWS, DHm, DHm, DD, DHm, DHm, 0,0,0);
  gemm_kernel<false,0><<<dim3(DHm/32, MROWS/32, 1), blk, 0, stream>>>(
      x+DHm,   wk2, bk2, Kb, MROWS, DHm, DHm, DD, DHm, DHm, 0,0,0);
  gemm_kernel<false,0><<<dim3(DHm/32, MROWS/32, 1), blk, 0, stream>>>(
      x+DHm,   wv2, bv2, Vb, MROWS, DHm, DHm, DD, DHm, DHm, 0,0,0);
  attn_kernel<2><<<dim3(SS, NH, BB), 256, 0, stream>>>(Qb, Kb, Vb, mask, dist, awg, CTX);
  gemm_kernel<false,0><<<dim3(DHm/32, MROWS/32, 1), blk, 0, stream>>>(
      CTX, wo2, bo2, XG, MROWS, DHm, DHm, DHm, DHm, DHm, 0,0,0);

  // ---- BAN ----
  gemm_kernel<false,1><<<dim3(DD/32, MROWS/32, 1), blk, 0, stream>>>(
      XL, vnet_w, vnet_b, Vn, MROWS, DD, DHm, DHm, DD, DD, 0,0,0);
  gemm_kernel<false,1><<<dim3(DD/32, MROWS/32, 1), blk, 0, stream>>>(
      XG, qnet_w, qnet_b, Qn, MROWS, DD, DHm, DHm, DD, DD, 0,0,0);
  vh_kernel<<<dim3((MROWS*DD)/256), 256, 0, stream>>>(Vn, h_mat, VH, MROWS*DD);
  // G[b] = vh[b] @ q_[b]^T
  gemm_kernel<true,0><<<dim3(SS/32, SS/32, BB), blk, 0, stream>>>(
      VH, Qn, (const float*)nullptr, G, SS, SS, DD, DD, DD, SS, GST, GST, GST);
  addhb_kernel<<<dim3((BB*SS*SS)/256), 256, 0, stream>>>(G, h_bias, BB*SS*SS);
  // T[b] = G[b] @ q_[b]
  gemm_kernel<false,0><<<dim3(DD/32, SS/32, BB), blk, 0, stream>>>(
      G, Qn, (const float*)nullptr, T, SS, DD, SS, SS, DD, DD, GST, GST, GST);

  // ---- BN + gate + residual + LN1 ----
  bn_gate_ln1_kernel<<<dim3(MROWS), 256, 0, stream>>>(
      x, Vn, T, XL, XG, bn_g, bn_b, bn_m, bn_v, ln1_g, ln1_b, OUT1);

  // ---- FFN ----
  gemm_kernel<false,2><<<dim3(DFF/32, MROWS/32, 1), blk, 0, stream>>>(
      OUT1, ffn_w1, ffn_b1, H, MROWS, DFF, DD, DD, DFF, DFF, 0,0,0);
  gemm_kernel<false,0><<<dim3(DD/32, MROWS/32, 1), blk, 0, stream>>>(
      H, ffn_w2, ffn_b2, FFNO, MROWS, DD, DFF, DFF, DD, DD, 0,0,0);

  // ---- residual + LN2 -> out ----
  ln2_kernel<<<dim3(MROWS), 256, 0, stream>>>(OUT1, FFNO, ln2_g, ln2_b, out2);
}

// Round 3
// 1061.394 us; speedup vs baseline: 2.0063x; 2.0063x over previous
//
#include <hip/hip_runtime.h>
#include <hip/hip_bf16.h>

typedef __hip_bfloat16 bf16;
typedef __attribute__((ext_vector_type(8))) short bf16x8;
typedef __attribute__((ext_vector_type(4))) float f32x4;

#define BB 8
#define SS 512
#define DD 512
#define NH 8
#define DHm 256
#define DEP 32
#define DFF 2048

// ================= MFMA bf16 GEMM: C = act(A @ op(B) + bias) =================
// 64x64 tile, BK=32, 256 threads = 4 waves (2x2), each wave 32x32 via 4x mfma_16x16x32.
// A: (M,K) fp32 or bf16; B: (K,N) fp32 (or (N,K) if TRANSB); C fp32 or bf16.
// All of M,N multiples of 64 and K multiple of 32 (true for every call site).
// LDS tiles hold bf16 with per-row XOR swizzle of the 8-element k-block so both
// the 16B staging stores and the ds_read_b128 fragment reads stay conflict-free.
template<typename TA, bool TRANSB, int ACT, typename TC>
__global__ __launch_bounds__(256)
void mfma_gemm(const TA* __restrict__ A, const float* __restrict__ B,
               const float* __restrict__ bias, TC* __restrict__ C,
               int M, int N, int K, int lda, int ldb, int ldc,
               long long sA, long long sB, long long sC)
{
  __shared__ bf16 As[64][32];
  __shared__ bf16 Bs[64][32];   // stored as [n][k]
  const int t = threadIdx.x;
  const int lane = t & 63, wave = t >> 6;
  const int wm = (wave & 1) << 5, wn = (wave >> 1) << 5;
  const int l15 = lane & 15, quad = lane >> 4;
  const int row0 = blockIdx.y << 6, col0 = blockIdx.x << 6;
  const TA* Ab = A + (long long)blockIdx.z * sA;
  const float* Bb = B + (long long)blockIdx.z * sB;
  TC* Cb = C + (long long)blockIdx.z * sC;

  // staging index plan (per thread): one 16B LDS store each for A and B
  const int ar  = t >> 2, acb = t & 3;                 // row-in-tile, k-block
  const int aswz = ((acb ^ ((ar >> 1) & 3)) << 3);
  const int bn  = t & 63, bkb = t >> 6;                // col n, k-block (non-trans B)
  const int bswz = ((bkb ^ ((bn >> 1) & 3)) << 3);

  f32x4 acc[2][2] = {};

  for (int k0 = 0; k0 < K; k0 += 32) {
    // ---- stage A (64 rows x 32 k) ----
    {
      union { bf16x8 v; bf16 h[8]; } u;
      if constexpr (sizeof(TA) == 2) {
        u.v = *(const bf16x8*)&Ab[(long long)(row0 + ar) * lda + k0 + (acb << 3)];
      } else {
        const float* p = (const float*)&Ab[(long long)(row0 + ar) * lda + k0 + (acb << 3)];
        float4 f0 = *(const float4*)p, f1 = *(const float4*)(p + 4);
        u.h[0]=__float2bfloat16(f0.x); u.h[1]=__float2bfloat16(f0.y);
        u.h[2]=__float2bfloat16(f0.z); u.h[3]=__float2bfloat16(f0.w);
        u.h[4]=__float2bfloat16(f1.x); u.h[5]=__float2bfloat16(f1.y);
        u.h[6]=__float2bfloat16(f1.z); u.h[7]=__float2bfloat16(f1.w);
      }
      *(bf16x8*)&As[ar][aswz] = u.v;
    }
    // ---- stage B -> Bs[n][k] ----
    if (TRANSB) {
      // B is (N,K): rows are contiguous in k, same plan as A
      const float* p = &Bb[(long long)(col0 + ar) * ldb + k0 + (acb << 3)];
      float4 f0 = *(const float4*)p, f1 = *(const float4*)(p + 4);
      union { bf16x8 v; bf16 h[8]; } u;
      u.h[0]=__float2bfloat16(f0.x); u.h[1]=__float2bfloat16(f0.y);
      u.h[2]=__float2bfloat16(f0.z); u.h[3]=__float2bfloat16(f0.w);
      u.h[4]=__float2bfloat16(f1.x); u.h[5]=__float2bfloat16(f1.y);
      u.h[6]=__float2bfloat16(f1.z); u.h[7]=__float2bfloat16(f1.w);
      *(bf16x8*)&Bs[ar][aswz] = u.v;
    } else {
      // B is (K,N): 8 coalesced dword loads (lanes sweep n), transpose into Bs
      union { bf16x8 v; bf16 h[8]; } u;
#pragma unroll
      for (int j = 0; j < 8; j++)
        u.h[j] = __float2bfloat16(Bb[(long long)(k0 + (bkb << 3) + j) * ldb + col0 + bn]);
      *(bf16x8*)&Bs[bn][bswz] = u.v;
    }
    __syncthreads();
    // ---- fragments + MFMA ----
    bf16x8 afr[2], bfr[2];
#pragma unroll
    for (int i = 0; i < 2; i++) {
      int m = wm + (i << 4) + l15;
      afr[i] = *(bf16x8*)&As[m][((quad ^ ((m >> 1) & 3)) << 3)];
      int n = wn + (i << 4) + l15;
      bfr[i] = *(bf16x8*)&Bs[n][((quad ^ ((n >> 1) & 3)) << 3)];
    }
#pragma unroll
    for (int i = 0; i < 2; i++)
#pragma unroll
      for (int j = 0; j < 2; j++)
        acc[i][j] = __builtin_amdgcn_mfma_f32_16x16x32_bf16(afr[i], bfr[j], acc[i][j], 0, 0, 0);
    __syncthreads();
  }

  // ---- epilogue: C/D layout col=lane&15, row=quad*4+reg ----
#pragma unroll
  for (int i = 0; i < 2; i++) {
#pragma unroll
    for (int j = 0; j < 2; j++) {
      int col = col0 + wn + (j << 4) + l15;
      float bv = bias ? bias[col] : 0.f;
#pragma unroll
      for (int r = 0; r < 4; r++) {
        int row = row0 + wm + (i << 4) + (quad << 2) + r;
        float v = acc[i][j][r] + bv;
        if (ACT == 1) v = fmaxf(v, 0.f);
        if (ACT == 2) v = 0.5f * v * (1.f + erff(v * 0.70710678118654752f));
        if constexpr (sizeof(TC) == 2) Cb[(long long)row * ldc + col] = __float2bfloat16(v);
        else                           Cb[(long long)row * ldc + col] = v;
      }
    }
  }
}

// ---------------- attention: one block per (b,h,q) ----------------
template<int BRANCH>
__global__ __launch_bounds__(256)
void attn_kernel(const float* __restrict__ Q, const float* __restrict__ K,
                 const float* __restrict__ V, const int* __restrict__ mask,
                 const float* __restrict__ extra, float* __restrict__ aw,
                 float* __restrict__ ctx)
{
  const int q = blockIdx.x, h = blockIdx.y, b = blockIdx.z;
  const int t = threadIdx.x;
  __shared__ float qv[DEP];
  __shared__ float sc[SS];
  __shared__ float red[256];
  if (t < DEP) qv[t] = Q[((long long)(b*SS+q))*DHm + h*DEP + t];
  __syncthreads();
  const float scale_inv = 0.17677669529663688f; // 1/sqrt(32)
  for (int k=t; k<SS; k+=256) {
    const float* kr = K + ((long long)(b*SS+k))*DHm + h*DEP;
    float s = 0.f;
#pragma unroll
    for (int d=0; d<DEP; d++) s += qv[d]*kr[d];
    float m = (float)mask[b*SS + k];
    float ev = extra[((long long)b*SS + q)*SS + k];
    if (BRANCH==1) {
      s = s*scale_inv + m*(-1e9f) + ev;
    } else {
      float resc = 3.7182818284590452f / (1.f + expf(1.f - ev));
      s = fmaxf(s, 0.f)*resc*scale_inv + m*(-1e9f);
    }
    sc[k] = s;
  }
  __syncthreads();
  float l0 = sc[t], l1 = sc[t+256];
  red[t] = fmaxf(l0, l1);
  __syncthreads();
  for (int o=128;o>0;o>>=1) { if (t<o) red[t] = fmaxf(red[t], red[t+o]); __syncthreads(); }
  float mx = red[0];
  __syncthreads();
  float e0 = expf(l0-mx), e1 = expf(l1-mx);
  red[t] = e0 + e1;
  __syncthreads();
  for (int o=128;o>0;o>>=1) { if (t<o) red[t] += red[t+o]; __syncthreads(); }
  float inv = 1.f/red[0];
  float p0 = e0*inv, p1 = e1*inv;
  sc[t] = p0; sc[t+256] = p1;
  long long awb = (((long long)b*NH + h)*SS + q)*SS;
  aw[awb + t]       = p0;
  aw[awb + t + 256] = p1;
  __syncthreads();
  int d = t & (DEP-1), part = t >> 5;
  float ps = 0.f;
  int k0 = part*64;
  for (int k=k0; k<k0+64; k++) ps += sc[k] * V[((long long)(b*SS+k))*DHm + h*DEP + d];
  red[t] = ps;
  __syncthreads();
  if (t < DEP) {
    float s2 = 0.f;
#pragma unroll
    for (int p=0;p<8;p++) s2 += red[p*32 + t];
    ctx[((long long)(b*SS+q))*DHm + h*DEP + t] = s2;
  }
}

// ---------------- vh = v_ * (h_mat[0,:]+h_mat[1,:]) ----------------
__global__ __launch_bounds__(256)
void vh_kernel(const float* __restrict__ v_, const float* __restrict__ hmat,
               float* __restrict__ vh, int n)
{
  int i = blockIdx.x*256 + threadIdx.x;
  if (i < n) {
    int c = i & (DD-1);
    vh[i] = v_[i] * (hmat[c] + hmat[DD + c]);
  }
}

// ---------------- G += h_bias[0]+h_bias[1] ----------------
__global__ __launch_bounds__(256)
void addhb_kernel(float* __restrict__ G, const float* __restrict__ hb, int n)
{
  int i = blockIdx.x*256 + threadIdx.x;
  if (i < n) G[i] += hb[0] + hb[1];
}

// ---------------- BN(eval) + gate + residual + LN1 (one block per row) ----------------
__global__ __launch_bounds__(256)
void bn_gate_ln1_kernel(const float* __restrict__ x, const float* __restrict__ vbuf,
                        const float* __restrict__ T, const float* __restrict__ xl,
                        const float* __restrict__ xg,
                        const float* __restrict__ bng, const float* __restrict__ bnb,
                        const float* __restrict__ bnm, const float* __restrict__ bnv,
                        const float* __restrict__ lng, const float* __restrict__ lnb,
                        float* __restrict__ out1)
{
  const int row = blockIdx.x;
  const int t = threadIdx.x;
  __shared__ float red[256];
  float val[2];
#pragma unroll
  for (int i=0;i<2;i++) {
    int c = t + i*256;
    long long idx = (long long)row*DD + c;
    float lg = vbuf[idx]*T[idx];
    float bn = (lg - bnm[c]) / sqrtf(bnv[c] + 1e-3f) * bng[c] + bnb[c];
    float gate = (c < DHm) ? xl[(long long)row*DHm + c] : xg[(long long)row*DHm + (c-DHm)];
    val[i] = x[idx] + bn*gate;
  }
  red[t] = val[0] + val[1];
  __syncthreads();
  for (int o=128;o>0;o>>=1) { if (t<o) red[t]+=red[t+o]; __syncthreads(); }
  float mu = red[0] * (1.f/512.f);
  __syncthreads();
  float d0 = val[0]-mu, d1 = val[1]-mu;
  red[t] = d0*d0 + d1*d1;
  __syncthreads();
  for (int o=128;o>0;o>>=1) { if (t<o) red[t]+=red[t+o]; __syncthreads(); }
  float inv = 1.f / sqrtf(red[0]*(1.f/512.f) + 1e-6f);
  out1[(long long)row*DD + t]       = d0*inv*lng[t]     + lnb[t];
  out1[(long long)row*DD + t + 256] = d1*inv*lng[t+256] + lnb[t+256];
}

// ---------------- residual + LN2 -> out ----------------
__global__ __launch_bounds__(256)
void ln2_kernel(const float* __restrict__ a, const float* __restrict__ b2,
                const float* __restrict__ g, const float* __restrict__ bta,
                float* __restrict__ out)
{
  const int row = blockIdx.x;
  const int t = threadIdx.x;
  __shared__ float red[256];
  float v0 = a[(long long)row*DD + t]       + b2[(long long)row*DD + t];
  float v1 = a[(long long)row*DD + t + 256] + b2[(long long)row*DD + t + 256];
  red[t] = v0 + v1;
  __syncthreads();
  for (int o=128;o>0;o>>=1) { if (t<o) red[t]+=red[t+o]; __syncthreads(); }
  float mu = red[0] * (1.f/512.f);
  __syncthreads();
  float d0 = v0-mu, d1 = v1-mu;
  red[t] = d0*d0 + d1*d1;
  __syncthreads();
  for (int o=128;o>0;o>>=1) { if (t<o) red[t]+=red[t+o]; __syncthreads(); }
  float inv = 1.f / sqrtf(red[0]*(1.f/512.f) + 1e-6f);
  out[(long long)row*DD + t]       = d0*inv*g[t]     + bta[t];
  out[(long long)row*DD + t + 256] = d1*inv*g[t+256] + bta[t+256];
}

extern "C" void kernel_launch(void* const* d_in, const int* in_sizes, int n_in,
                              void* d_out, int out_size, void* d_ws, size_t ws_size,
                              hipStream_t stream) {
  const float* x      = (const float*)d_in[0];
  const float* adjoin = (const float*)d_in[1];
  const float* dist   = (const float*)d_in[2];
  const float* wq1=(const float*)d_in[3],  *bq1=(const float*)d_in[4];
  const float* wk1=(const float*)d_in[5],  *bk1=(const float*)d_in[6];
  const float* wv1=(const float*)d_in[7],  *bv1=(const float*)d_in[8];
  const float* wo1=(const float*)d_in[9],  *bo1=(const float*)d_in[10];
  const float* wq2=(const float*)d_in[11], *bq2=(const float*)d_in[12];
  const float* wk2=(const float*)d_in[13], *bk2=(const float*)d_in[14];
  const float* wv2=(const float*)d_in[15], *bv2=(const float*)d_in[16];
  const float* wo2=(const float*)d_in[17], *bo2=(const float*)d_in[18];
  const float* vnet_w=(const float*)d_in[19], *vnet_b=(const float*)d_in[20];
  const float* qnet_w=(const float*)d_in[21], *qnet_b=(const float*)d_in[22];
  const float* h_mat=(const float*)d_in[23], *h_bias=(const float*)d_in[24];
  const float* bn_g=(const float*)d_in[25], *bn_b=(const float*)d_in[26];
  const float* bn_m=(const float*)d_in[27], *bn_v=(const float*)d_in[28];
  const float* ln1_g=(const float*)d_in[29], *ln1_b=(const float*)d_in[30];
  const float* ln2_g=(const float*)d_in[31], *ln2_b=(const float*)d_in[32];
  const float* ffn_w1=(const float*)d_in[33], *ffn_b1=(const float*)d_in[34];
  const float* ffn_w2=(const float*)d_in[35], *ffn_b2=(const float*)d_in[36];
  const int* mask = (const int*)d_in[37];

  float* ws = (float*)d_ws;
  const long long M1 = 1048576LL; // 1M floats
  float* Qb   = ws + 0*M1;   // (4096,256)          phase 1-2
  float* Kb   = ws + 1*M1;
  float* Vb   = ws + 2*M1;
  float* CTX  = ws + 3*M1;   // (4096,256)
  float* XL   = ws + 4*M1;   // live until bn_gate
  float* XG   = ws + 5*M1;
  float* Vn   = ws + 6*M1;   // v_ (4096,512) 6-8   live until bn_gate
  float* Qn   = ws + 8*M1;   // q_ (4096,512) 8-10  live until T gemm
  float* VH   = ws + 0*M1;   // (4096,512)   0-2    overlays Qb/Kb (dead)
  float* G    = ws + 2*M1;   // (8,512,512)  2-4    overlays Vb/CTX (dead)
  float* T    = ws + 10*M1;  // (4096,512)  10-12
  float* OUT1 = ws + 0*M1;   // (4096,512)   0-2    overlays VH (dead)
  bf16*  H    = (bf16*)(ws + 2*M1); // (4096,2048) bf16 = 4M floats, 2-6; overlays G (dead)
  float* FFNO = ws + 10*M1;  // (4096,512)  10-12   overlays T (dead)

  float* out2 = (float*)d_out;
  float* awl  = out2 + 2097152LL;
  float* awg  = awl + 16777216LL;

  const int MROWS = BB*SS; // 4096
  const long long GST = (long long)SS*SS; // 262144

  // ---- branch 1 (local / adjoin) ----
  mfma_gemm<float,false,0,float><<<dim3(DHm/64, MROWS/64, 1), 256, 0, stream>>>(
      x,   wq1, bq1, Qb, MROWS, DHm, DHm, DD, DHm, DHm, 0,0,0);
  mfma_gemm<float,false,0,float><<<dim3(DHm/64, MROWS/64, 1), 256, 0, stream>>>(
      x,   wk1, bk1, Kb, MROWS, DHm, DHm, DD, DHm, DHm, 0,0,0);
  mfma_gemm<float,false,0,float><<<dim3(DHm/64, MROWS/64, 1), 256, 0, stream>>>(
      x,   wv1, bv1, Vb, MROWS, DHm, DHm, DD, DHm, DHm, 0,0,0);
  attn_kernel<1><<<dim3(SS, NH, BB), 256, 0, stream>>>(Qb, Kb, Vb, mask, adjoin, awl, CTX);
  mfma_gemm<float,false,0,float><<<dim3(DHm/64, MROWS/64, 1), 256, 0, stream>>>(
      CTX, wo1, bo1, XL, MROWS, DHm, DHm, DHm, DHm, DHm, 0,0,0);

  // ---- branch 2 (global / distance) ----
  mfma_gemm<float,false,0,float><<<dim3(DHm/64, MROWS/64, 1), 256, 0, stream>>>(
      x+DHm, wq2, bq2, Qb, MROWS, DHm, DHm, DD, DHm, DHm, 0,0,0);
  mfma_gemm<float,false,0,float><<<dim3(DHm/64, MROWS/64, 1), 256, 0, stream>>>(
      x+DHm, wk2, bk2, Kb, MROWS, DHm, DHm, DD, DHm, DHm, 0,0,0);
  mfma_gemm<float,false,0,float><<<dim3(DHm/64, MROWS/64, 1), 256, 0, stream>>>(
      x+DHm, wv2, bv2, Vb, MROWS, DHm, DHm, DD, DHm, DHm, 0,0,0);
  attn_kernel<2><<<dim3(SS, NH, BB), 256, 0, stream>>>(Qb, Kb, Vb, mask, dist, awg, CTX);
  mfma_gemm<float,false,0,float><<<dim3(DHm/64, MROWS/64, 1), 256, 0, stream>>>(
      CTX, wo2, bo2, XG, MROWS, DHm, DHm, DHm, DHm, DHm, 0,0,0);

  // ---- BAN ----
  mfma_gemm<float,false,1,float><<<dim3(DD/64, MROWS/64, 1), 256, 0, stream>>>(
      XL, vnet_w, vnet_b, Vn, MROWS, DD, DHm, DHm, DD, DD, 0,0,0);
  mfma_gemm<float,false,1,float><<<dim3(DD/64, MROWS/64, 1), 256, 0, stream>>>(
      XG, qnet_w, qnet_b, Qn, MROWS, DD, DHm, DHm, DD, DD, 0,0,0);
  vh_kernel<<<dim3((MROWS*DD)/256), 256, 0, stream>>>(Vn, h_mat, VH, MROWS*DD);
  // G[b] = vh[b] @ q_[b]^T   (TRANSB: B is (N,K) rows contiguous in k)
  mfma_gemm<float,true,0,float><<<dim3(SS/64, SS/64, BB), 256, 0, stream>>>(
      VH, Qn, (const float*)nullptr, G, SS, SS, DD, DD, DD, SS, GST, GST, GST);
  addhb_kernel<<<dim3((BB*SS*SS)/256), 256, 0, stream>>>(G, h_bias, BB*SS*SS);
  // T[b] = G[b] @ q_[b]
  mfma_gemm<float,false,0,float><<<dim3(DD/64, SS/64, BB), 256, 0, stream>>>(
      G, Qn, (const float*)nullptr, T, SS, DD, SS, SS, DD, DD, GST, GST, GST);

  // ---- BN + gate + residual + LN1 ----
  bn_gate_ln1_kernel<<<dim3(MROWS), 256, 0, stream>>>(
      x, Vn, T, XL, XG, bn_g, bn_b, bn_m, bn_v, ln1_g, ln1_b, OUT1);

  // ---- FFN (H kept in bf16 between the two GEMMs) ----
  mfma_gemm<float,false,2,bf16><<<dim3(DFF/64, MROWS/64, 1), 256, 0, stream>>>(
      OUT1, ffn_w1, ffn_b1, H, MROWS, DFF, DD, DD, DFF, DFF, 0,0,0);
  mfma_gemm<bf16,false,0,float><<<dim3(DD/64, MROWS/64, 1), 256, 0, stream>>>(
      H, ffn_w2, ffn_b2, FFNO, MROWS, DD, DFF, DFF, DD, DD, 0,0,0);

  // ---- residual + LN2 -> out ----
  ln2_kernel<<<dim3(MROWS), 256, 0, stream>>>(OUT1, FFNO, ln2_g, ln2_b, out2);
}

// Round 4
// 528.706 us; speedup vs baseline: 4.0276x; 2.0075x over previous
//
#include <hip/hip_runtime.h>
#include <hip/hip_bf16.h>

typedef __hip_bfloat16 bf16;
typedef __attribute__((ext_vector_type(8))) short bf16x8;
typedef __attribute__((ext_vector_type(4))) float f32x4;

#define BB 8
#define SS 512
#define DD 512
#define NH 8
#define DHm 256
#define DEP 32
#define DFF 2048

__device__ __forceinline__ bf16x8 cvt8(const float* p) {
  union { bf16x8 v; bf16 h[8]; } u;
  float4 f0 = *(const float4*)p, f1 = *(const float4*)(p + 4);
  u.h[0]=__float2bfloat16(f0.x); u.h[1]=__float2bfloat16(f0.y);
  u.h[2]=__float2bfloat16(f0.z); u.h[3]=__float2bfloat16(f0.w);
  u.h[4]=__float2bfloat16(f1.x); u.h[5]=__float2bfloat16(f1.y);
  u.h[6]=__float2bfloat16(f1.z); u.h[7]=__float2bfloat16(f1.w);
  return u.v;
}

// ================= MFMA bf16 GEMM: C = act(A @ op(B) + bias) =================
// 64x64 tile, BK=32, 256 threads = 4 waves (2x2), each wave 32x32 via 4x mfma_16x16x32.
template<typename TA, bool TRANSB, int ACT, typename TC>
__global__ __launch_bounds__(256)
void mfma_gemm(const TA* __restrict__ A, const float* __restrict__ B,
               const float* __restrict__ bias, TC* __restrict__ C,
               int M, int N, int K, int lda, int ldb, int ldc,
               long long sA, long long sB, long long sC)
{
  __shared__ bf16 As[64][32];
  __shared__ bf16 Bs[64][32];   // stored as [n][k]
  const int t = threadIdx.x;
  const int lane = t & 63, wave = t >> 6;
  const int wm = (wave & 1) << 5, wn = (wave >> 1) << 5;
  const int l15 = lane & 15, quad = lane >> 4;
  const int row0 = blockIdx.y << 6, col0 = blockIdx.x << 6;
  const TA* Ab = A + (long long)blockIdx.z * sA;
  const float* Bb = B + (long long)blockIdx.z * sB;
  TC* Cb = C + (long long)blockIdx.z * sC;

  const int ar  = t >> 2, acb = t & 3;
  const int aswz = ((acb ^ ((ar >> 1) & 3)) << 3);
  const int bn  = t & 63, bkb = t >> 6;
  const int bswz = ((bkb ^ ((bn >> 1) & 3)) << 3);

  f32x4 acc[2][2] = {};

  for (int k0 = 0; k0 < K; k0 += 32) {
    {
      union { bf16x8 v; bf16 h[8]; } u;
      if constexpr (sizeof(TA) == 2) {
        u.v = *(const bf16x8*)&Ab[(long long)(row0 + ar) * lda + k0 + (acb << 3)];
      } else {
        u.v = cvt8((const float*)&Ab[(long long)(row0 + ar) * lda + k0 + (acb << 3)]);
      }
      *(bf16x8*)&As[ar][aswz] = u.v;
    }
    if (TRANSB) {
      *(bf16x8*)&Bs[ar][aswz] = cvt8(&Bb[(long long)(col0 + ar) * ldb + k0 + (acb << 3)]);
    } else {
      union { bf16x8 v; bf16 h[8]; } u;
#pragma unroll
      for (int j = 0; j < 8; j++)
        u.h[j] = __float2bfloat16(Bb[(long long)(k0 + (bkb << 3) + j) * ldb + col0 + bn]);
      *(bf16x8*)&Bs[bn][bswz] = u.v;
    }
    __syncthreads();
    bf16x8 afr[2], bfr[2];
#pragma unroll
    for (int i = 0; i < 2; i++) {
      int m = wm + (i << 4) + l15;
      afr[i] = *(bf16x8*)&As[m][((quad ^ ((m >> 1) & 3)) << 3)];
      int n = wn + (i << 4) + l15;
      bfr[i] = *(bf16x8*)&Bs[n][((quad ^ ((n >> 1) & 3)) << 3)];
    }
#pragma unroll
    for (int i = 0; i < 2; i++)
#pragma unroll
      for (int j = 0; j < 2; j++)
        acc[i][j] = __builtin_amdgcn_mfma_f32_16x16x32_bf16(afr[i], bfr[j], acc[i][j], 0, 0, 0);
    __syncthreads();
  }

#pragma unroll
  for (int i = 0; i < 2; i++) {
#pragma unroll
    for (int j = 0; j < 2; j++) {
      int col = col0 + wn + (j << 4) + l15;
      float bv = bias ? bias[col] : 0.f;
#pragma unroll
      for (int r = 0; r < 4; r++) {
        int row = row0 + wm + (i << 4) + (quad << 2) + r;
        float v = acc[i][j][r] + bv;
        if (ACT == 1) v = fmaxf(v, 0.f);
        if (ACT == 2) v = 0.5f * v * (1.f + erff(v * 0.70710678118654752f));
        if constexpr (sizeof(TC) == 2) Cb[(long long)row * ldc + col] = __float2bfloat16(v);
        else                           Cb[(long long)row * ldc + col] = v;
      }
    }
  }
}

// ================= MFMA attention =================
// Block = (qtile 64, h, b); 4 waves; wave handles a 16-q-row strip.
// QKV: (4096, 768) packed [Q|K|V] per branch. aw fp32 (B,NH,S,S); ctx (4096,256).
template<int BRANCH>
__global__ __launch_bounds__(256, 2)
void attn_mfma(const float* __restrict__ QKV, const int* __restrict__ mask,
               const float* __restrict__ extra, float* __restrict__ aw,
               float* __restrict__ ctx)
{
  const int qt = blockIdx.x, h = blockIdx.y, b = blockIdx.z;
  const int t = threadIdx.x, lane = t & 63, wave = t >> 6;
  const int l15 = lane & 15, quad = lane >> 4;
  __shared__ bf16x8 Vt[64][32];   // [kpos-block of 8][dep], 32 KB

  // ---- stage V transposed+blocked: Vt[blk][dep] = V[blk*8..+8][dep] ----
  {
    const float* Vb = QKV + (long long)b * SS * 768 + 512 + h * 32;
    int dep = t & 31;
#pragma unroll
    for (int j8 = 0; j8 < 8; j8++) {
      int blk = (t >> 5) + (j8 << 3);
      union { bf16x8 v; bf16 hh[8]; } u;
#pragma unroll
      for (int i = 0; i < 8; i++)
        u.hh[i] = __float2bfloat16(Vb[(long long)(blk * 8 + i) * 768 + dep]);
      Vt[blk][dep] = u.v;
    }
  }

  // ---- Q fragment (A-layout: m=l15 row, k=quad*8+j dep) ----
  const int q0 = qt * 64 + wave * 16;
  const float* Qb = QKV + ((long long)(b * SS + q0)) * 768 + h * 32;
  bf16x8 qfrag = cvt8(Qb + (long long)l15 * 768 + quad * 8);
  __syncthreads();

  // ---- scores: 32 chunks of 16 kpos ----
  const float scale_inv = 0.17677669529663688f; // 1/sqrt(32)
  const float* Kb = QKV + (long long)b * SS * 768 + 256 + h * 32;
  const float* Eb = extra + ((long long)b * SS + q0) * SS;
  float sreg[32][4];
  float rmax[4] = {-1e30f, -1e30f, -1e30f, -1e30f};
#pragma unroll
  for (int kc = 0; kc < 32; kc++) {
    int kpos = kc * 16 + l15;
    bf16x8 kfrag = cvt8(Kb + (long long)kpos * 768 + quad * 8);
    f32x4 a = __builtin_amdgcn_mfma_f32_16x16x32_bf16(qfrag, kfrag, f32x4{0.f,0.f,0.f,0.f}, 0, 0, 0);
    float mval = (float)mask[b * SS + kpos] * -1e9f;
#pragma unroll
    for (int r = 0; r < 4; r++) {
      float s = a[r];
      float ev = Eb[(long long)(quad * 4 + r) * SS + kpos];
      if (BRANCH == 1) {
        s = s * scale_inv + mval + ev;
      } else {
        float resc = 3.7182818284590452f / (1.f + __expf(1.f - ev));
        s = fmaxf(s, 0.f) * resc * scale_inv + mval;
      }
      sreg[kc][r] = s;
      rmax[r] = fmaxf(rmax[r], s);
    }
  }
  // ---- softmax (rows live within a 16-lane quad) ----
#pragma unroll
  for (int r = 0; r < 4; r++) {
    float v = rmax[r];
    v = fmaxf(v, __shfl_xor(v, 1, 16));
    v = fmaxf(v, __shfl_xor(v, 2, 16));
    v = fmaxf(v, __shfl_xor(v, 4, 16));
    v = fmaxf(v, __shfl_xor(v, 8, 16));
    rmax[r] = v;
  }
  float rsum[4] = {0.f, 0.f, 0.f, 0.f};
#pragma unroll
  for (int kc = 0; kc < 32; kc++)
#pragma unroll
    for (int r = 0; r < 4; r++) {
      float e = __expf(sreg[kc][r] - rmax[r]);
      sreg[kc][r] = e;
      rsum[r] += e;
    }
#pragma unroll
  for (int r = 0; r < 4; r++) {
    float v = rsum[r];
    v += __shfl_xor(v, 1, 16);
    v += __shfl_xor(v, 2, 16);
    v += __shfl_xor(v, 4, 16);
    v += __shfl_xor(v, 8, 16);
    rsum[r] = 1.f / v;
  }
  // ---- write aw (normalized) ----
  float* awp = aw + (((long long)(b * NH + h) * SS + q0)) * SS;
#pragma unroll
  for (int kc = 0; kc < 32; kc++)
#pragma unroll
    for (int r = 0; r < 4; r++)
      awp[(long long)(quad * 4 + r) * SS + kc * 16 + l15] = sreg[kc][r] * rsum[r];

  // ensure this wave's aw stores reached L2 before re-reading
  asm volatile("s_waitcnt vmcnt(0)" ::: "memory");

  // ---- PV: O(16q x 32dep) from aw (A) and Vt (B) ----
  f32x4 oacc[2] = {};
#pragma unroll
  for (int kc2 = 0; kc2 < 16; kc2++) {
    bf16x8 afr = cvt8(awp + (long long)l15 * SS + kc2 * 32 + quad * 8);
#pragma unroll
    for (int n = 0; n < 2; n++) {
      bf16x8 bfr = Vt[kc2 * 4 + quad][n * 16 + l15];
      oacc[n] = __builtin_amdgcn_mfma_f32_16x16x32_bf16(afr, bfr, oacc[n], 0, 0, 0);
    }
  }
#pragma unroll
  for (int n = 0; n < 2; n++)
#pragma unroll
    for (int r = 0; r < 4; r++) {
      int q = q0 + quad * 4 + r;
      ctx[(long long)(b * SS + q) * DHm + h * 32 + n * 16 + l15] = oacc[n][r];
    }
}

// ---------------- pack [wq|wk|wv] -> WB (256 x 768), biases -> BBo (768) ----------------
__global__ __launch_bounds__(256)
void pack_qkv(const float* __restrict__ wq, const float* __restrict__ wk,
              const float* __restrict__ wv, const float* __restrict__ bq,
              const float* __restrict__ bk, const float* __restrict__ bv,
              float* __restrict__ WB, float* __restrict__ BBo)
{
  int idx = blockIdx.x * 256 + threadIdx.x;
  if (idx < 768 * 256) {
    int k = idx / 768, c = idx % 768;
    int part = c >> 8, n = c & 255;
    const float* w = part == 0 ? wq : (part == 1 ? wk : wv);
    WB[idx] = w[k * 256 + n];
  } else if (idx < 768 * 256 + 768) {
    int c = idx - 768 * 256;
    int part = c >> 8, n = c & 255;
    const float* bs = part == 0 ? bq : (part == 1 ? bk : bv);
    BBo[c] = bs[n];
  }
}

// ---------------- vh = v_ * (h_mat[0,:]+h_mat[1,:]) ----------------
__global__ __launch_bounds__(256)
void vh_kernel(const float* __restrict__ v_, const float* __restrict__ hmat,
               float* __restrict__ vh, int n)
{
  int i = blockIdx.x * 256 + threadIdx.x;
  if (i < n) {
    int c = i & (DD - 1);
    vh[i] = v_[i] * (hmat[c] + hmat[DD + c]);
  }
}

// ---------------- G += h_bias[0]+h_bias[1] ----------------
__global__ __launch_bounds__(256)
void addhb_kernel(float* __restrict__ G, const float* __restrict__ hb, int n)
{
  int i = blockIdx.x * 256 + threadIdx.x;
  if (i < n) G[i] += hb[0] + hb[1];
}

// ---------------- BN(eval) + gate + residual + LN1 ----------------
__global__ __launch_bounds__(256)
void bn_gate_ln1_kernel(const float* __restrict__ x, const float* __restrict__ vbuf,
                        const float* __restrict__ T, const float* __restrict__ xl,
                        const float* __restrict__ xg,
                        const float* __restrict__ bng, const float* __restrict__ bnb,
                        const float* __restrict__ bnm, const float* __restrict__ bnv,
                        const float* __restrict__ lng, const float* __restrict__ lnb,
                        float* __restrict__ out1)
{
  const int row = blockIdx.x;
  const int t = threadIdx.x;
  __shared__ float red[256];
  float val[2];
#pragma unroll
  for (int i = 0; i < 2; i++) {
    int c = t + i * 256;
    long long idx = (long long)row * DD + c;
    float lg = vbuf[idx] * T[idx];
    float bn = (lg - bnm[c]) / sqrtf(bnv[c] + 1e-3f) * bng[c] + bnb[c];
    float gate = (c < DHm) ? xl[(long long)row * DHm + c] : xg[(long long)row * DHm + (c - DHm)];
    val[i] = x[idx] + bn * gate;
  }
  red[t] = val[0] + val[1];
  __syncthreads();
  for (int o = 128; o > 0; o >>= 1) { if (t < o) red[t] += red[t + o]; __syncthreads(); }
  float mu = red[0] * (1.f / 512.f);
  __syncthreads();
  float d0 = val[0] - mu, d1 = val[1] - mu;
  red[t] = d0 * d0 + d1 * d1;
  __syncthreads();
  for (int o = 128; o > 0; o >>= 1) { if (t < o) red[t] += red[t + o]; __syncthreads(); }
  float inv = 1.f / sqrtf(red[0] * (1.f / 512.f) + 1e-6f);
  out1[(long long)row * DD + t]       = d0 * inv * lng[t]       + lnb[t];
  out1[(long long)row * DD + t + 256] = d1 * inv * lng[t + 256] + lnb[t + 256];
}

// ---------------- residual + LN2 -> out ----------------
__global__ __launch_bounds__(256)
void ln2_kernel(const float* __restrict__ a, const float* __restrict__ b2,
                const float* __restrict__ g, const float* __restrict__ bta,
                float* __restrict__ out)
{
  const int row = blockIdx.x;
  const int t = threadIdx.x;
  __shared__ float red[256];
  float v0 = a[(long long)row * DD + t]       + b2[(long long)row * DD + t];
  float v1 = a[(long long)row * DD + t + 256] + b2[(long long)row * DD + t + 256];
  red[t] = v0 + v1;
  __syncthreads();
  for (int o = 128; o > 0; o >>= 1) { if (t < o) red[t] += red[t + o]; __syncthreads(); }
  float mu = red[0] * (1.f / 512.f);
  __syncthreads();
  float d0 = v0 - mu, d1 = v1 - mu;
  red[t] = d0 * d0 + d1 * d1;
  __syncthreads();
  for (int o = 128; o > 0; o >>= 1) { if (t < o) red[t] += red[t + o]; __syncthreads(); }
  float inv = 1.f / sqrtf(red[0] * (1.f / 512.f) + 1e-6f);
  out[(long long)row * DD + t]       = d0 * inv * g[t]       + bta[t];
  out[(long long)row * DD + t + 256] = d1 * inv * g[t + 256] + bta[t + 256];
}

extern "C" void kernel_launch(void* const* d_in, const int* in_sizes, int n_in,
                              void* d_out, int out_size, void* d_ws, size_t ws_size,
                              hipStream_t stream) {
  const float* x      = (const float*)d_in[0];
  const float* adjoin = (const float*)d_in[1];
  const float* dist   = (const float*)d_in[2];
  const float* wq1=(const float*)d_in[3],  *bq1=(const float*)d_in[4];
  const float* wk1=(const float*)d_in[5],  *bk1=(const float*)d_in[6];
  const float* wv1=(const float*)d_in[7],  *bv1=(const float*)d_in[8];
  const float* wo1=(const float*)d_in[9],  *bo1=(const float*)d_in[10];
  const float* wq2=(const float*)d_in[11], *bq2=(const float*)d_in[12];
  const float* wk2=(const float*)d_in[13], *bk2=(const float*)d_in[14];
  const float* wv2=(const float*)d_in[15], *bv2=(const float*)d_in[16];
  const float* wo2=(const float*)d_in[17], *bo2=(const float*)d_in[18];
  const float* vnet_w=(const float*)d_in[19], *vnet_b=(const float*)d_in[20];
  const float* qnet_w=(const float*)d_in[21], *qnet_b=(const float*)d_in[22];
  const float* h_mat=(const float*)d_in[23], *h_bias=(const float*)d_in[24];
  const float* bn_g=(const float*)d_in[25], *bn_b=(const float*)d_in[26];
  const float* bn_m=(const float*)d_in[27], *bn_v=(const float*)d_in[28];
  const float* ln1_g=(const float*)d_in[29], *ln1_b=(const float*)d_in[30];
  const float* ln2_g=(const float*)d_in[31], *ln2_b=(const float*)d_in[32];
  const float* ffn_w1=(const float*)d_in[33], *ffn_b1=(const float*)d_in[34];
  const float* ffn_w2=(const float*)d_in[35], *ffn_b2=(const float*)d_in[36];
  const int* mask = (const int*)d_in[37];

  float* ws = (float*)d_ws;
  const long long M1 = 1048576LL;
  float* QKV1 = ws + 0 * M1;       // (4096,768) 0-3
  float* QKV2 = ws + 3 * M1;       // 3-6
  float* CTX  = ws + 6 * M1;       // (4096,256) 6-7
  float* XL   = ws + 7 * M1;       // 7-8, live until bn_gate
  float* XG   = ws + 8 * M1;       // 8-9
  float* Vn   = ws + 9 * M1;       // (4096,512) 9-11, live until bn_gate
  float* Qn   = ws + 11 * M1;      // 11-13, live until T gemm
  float* WB1  = ws + 13 * M1;      // pack: consumed at start
  float* BB1v = WB1 + 196608;
  float* WB2  = BB1v + 768;
  float* BB2v = WB2 + 196608;
  float* VH   = ws + 0 * M1;       // 0-2 (QKV1 dead after attn1... kept: after both attns)
  float* G    = ws + 3 * M1;       // 3-5 (QKV2 dead after attn2)
  float* T    = ws + 13 * M1;      // 13-14 (pack dead)
  float* OUT1 = ws + 0 * M1;       // 0-1 (VH dead after G gemm)
  bf16*  H    = (bf16*)(ws + 3 * M1); // (4096,2048) bf16 = 4M floats, 3-7 (G/CTX dead)
  float* FFNO = ws + 7 * M1;       // 7-8 (XL dead after bn_gate)

  float* out2 = (float*)d_out;
  float* awl  = out2 + 2097152LL;
  float* awg  = awl + 16777216LL;

  const int MROWS = BB * SS; // 4096
  const long long GST = (long long)SS * SS;

  // ---- pack QKV weights ----
  pack_qkv<<<dim3(771), 256, 0, stream>>>(wq1, wk1, wv1, bq1, bk1, bv1, WB1, BB1v);
  pack_qkv<<<dim3(771), 256, 0, stream>>>(wq2, wk2, wv2, bq2, bk2, bv2, WB2, BB2v);

  // ---- branch 1 (local / adjoin) ----
  mfma_gemm<float,false,0,float><<<dim3(768/64, MROWS/64, 1), 256, 0, stream>>>(
      x, WB1, BB1v, QKV1, MROWS, 768, DHm, DD, 768, 768, 0,0,0);
  attn_mfma<1><<<dim3(8, NH, BB), 256, 0, stream>>>(QKV1, mask, adjoin, awl, CTX);
  mfma_gemm<float,false,0,float><<<dim3(DHm/64, MROWS/64, 1), 256, 0, stream>>>(
      CTX, wo1, bo1, XL, MROWS, DHm, DHm, DHm, DHm, DHm, 0,0,0);

  // ---- branch 2 (global / distance) ----
  mfma_gemm<float,false,0,float><<<dim3(768/64, MROWS/64, 1), 256, 0, stream>>>(
      x + DHm, WB2, BB2v, QKV2, MROWS, 768, DHm, DD, 768, 768, 0,0,0);
  attn_mfma<2><<<dim3(8, NH, BB), 256, 0, stream>>>(QKV2, mask, dist, awg, CTX);
  mfma_gemm<float,false,0,float><<<dim3(DHm/64, MROWS/64, 1), 256, 0, stream>>>(
      CTX, wo2, bo2, XG, MROWS, DHm, DHm, DHm, DHm, DHm, 0,0,0);

  // ---- BAN ----
  mfma_gemm<float,false,1,float><<<dim3(DD/64, MROWS/64, 1), 256, 0, stream>>>(
      XL, vnet_w, vnet_b, Vn, MROWS, DD, DHm, DHm, DD, DD, 0,0,0);
  mfma_gemm<float,false,1,float><<<dim3(DD/64, MROWS/64, 1), 256, 0, stream>>>(
      XG, qnet_w, qnet_b, Qn, MROWS, DD, DHm, DHm, DD, DD, 0,0,0);
  vh_kernel<<<dim3((MROWS*DD)/256), 256, 0, stream>>>(Vn, h_mat, VH, MROWS*DD);
  mfma_gemm<float,true,0,float><<<dim3(SS/64, SS/64, BB), 256, 0, stream>>>(
      VH, Qn, (const float*)nullptr, G, SS, SS, DD, DD, DD, SS, GST, GST, GST);
  addhb_kernel<<<dim3((BB*SS*SS)/256), 256, 0, stream>>>(G, h_bias, BB*SS*SS);
  mfma_gemm<float,false,0,float><<<dim3(DD/64, SS/64, BB), 256, 0, stream>>>(
      G, Qn, (const float*)nullptr, T, SS, DD, SS, SS, DD, DD, GST, GST, GST);

  // ---- BN + gate + residual + LN1 ----
  bn_gate_ln1_kernel<<<dim3(MROWS), 256, 0, stream>>>(
      x, Vn, T, XL, XG, bn_g, bn_b, bn_m, bn_v, ln1_g, ln1_b, OUT1);

  // ---- FFN ----
  mfma_gemm<float,false,2,bf16><<<dim3(DFF/64, MROWS/64, 1), 256, 0, stream>>>(
      OUT1, ffn_w1, ffn_b1, H, MROWS, DFF, DD, DD, DFF, DFF, 0,0,0);
  mfma_gemm<bf16,false,0,float><<<dim3(DD/64, MROWS/64, 1), 256, 0, stream>>>(
      H, ffn_w2, ffn_b2, FFNO, MROWS, DD, DFF, DFF, DD, DD, 0,0,0);

  // ---- residual + LN2 -> out ----
  ln2_kernel<<<dim3(MROWS), 256, 0, stream>>>(OUT1, FFNO, ln2_g, ln2_b, out2);
}

// Round 5
// 451.113 us; speedup vs baseline: 4.7204x; 1.1720x over previous
//
#include <hip/hip_runtime.h>
#include <hip/hip_bf16.h>

typedef __hip_bfloat16 bf16;
typedef __attribute__((ext_vector_type(8))) short bf16x8;
typedef __attribute__((ext_vector_type(4))) float f32x4;

#define BB 8
#define SS 512
#define DD 512
#define NH 8
#define DHm 256
#define DFF 2048

__device__ __forceinline__ void gl_lds16(const void* g, void* l) {
  __builtin_amdgcn_global_load_lds((const __attribute__((address_space(1))) void*)g,
                                   (__attribute__((address_space(3))) void*)l, 16, 0, 0);
}

__device__ __forceinline__ bf16x8 cvt8(const float* p) {
  union { bf16x8 v; bf16 h[8]; } u;
  float4 f0 = *(const float4*)p, f1 = *(const float4*)(p + 4);
  u.h[0]=__float2bfloat16(f0.x); u.h[1]=__float2bfloat16(f0.y);
  u.h[2]=__float2bfloat16(f0.z); u.h[3]=__float2bfloat16(f0.w);
  u.h[4]=__float2bfloat16(f1.x); u.h[5]=__float2bfloat16(f1.y);
  u.h[6]=__float2bfloat16(f1.z); u.h[7]=__float2bfloat16(f1.w);
  return u.v;
}

// ================= bf16 MFMA GEMM (m97-style staging) =================
// A (M,K) bf16 row-major; B (N,K) bf16 row-major (pre-transposed weights).
// Block tile BM x BN, BK=32; 4 waves (2x2); global_load_lds width-16 staging.
// SMODE: 1=fp32 store, 2=bf16 store, 3=both. BIASM: 0 none, 1 per-col fp32, 2 scalar bias[0]+bias[1].
template<int BM, int BN, int SMODE, int BIASM, int ACT>
__global__ __launch_bounds__(256)
void gemm2(const bf16* __restrict__ A, const bf16* __restrict__ B,
           const float* __restrict__ bias, float* __restrict__ Cf,
           bf16* __restrict__ Cb, int K, int lda, int ldb, int ldc,
           long long sA, long long sB, long long sC)
{
  __shared__ bf16 As[BM * 32];
  __shared__ bf16 Bs[BN * 32];
  const int t = threadIdx.x, lane = t & 63, wave = t >> 6;
  const int l15 = lane & 15, quad = lane >> 4;
  constexpr int WMT = BM / 32, WNT = BN / 32;    // 16-tiles per wave in m/n
  const int wm = (wave & 1) * (BM / 2), wn = (wave >> 1) * (BN / 2);
  const int row0 = blockIdx.y * BM, col0 = blockIdx.x * BN;
  const bf16* Ab = A + (long long)blockIdx.z * sA + (long long)row0 * lda;
  const bf16* Bb = B + (long long)blockIdx.z * sB + (long long)col0 * ldb;
  const int srow = wave * 16 + (lane >> 2), skc = (lane & 3) << 3;

  f32x4 acc[WMT][WNT] = {};

  for (int k0 = 0; k0 < K; k0 += 32) {
#pragma unroll
    for (int j = 0; j < BM / 64; j++)
      gl_lds16(Ab + (long long)(srow + j * 64) * lda + k0 + skc,
               (char*)As + wave * 1024 + j * 4096);
#pragma unroll
    for (int j = 0; j < BN / 64; j++)
      gl_lds16(Bb + (long long)(srow + j * 64) * ldb + k0 + skc,
               (char*)Bs + wave * 1024 + j * 4096);
    __syncthreads();
    bf16x8 af[WMT], bfr[WNT];
#pragma unroll
    for (int i = 0; i < WMT; i++) af[i]  = *(const bf16x8*)&As[(wm + i * 16 + l15) * 32 + quad * 8];
#pragma unroll
    for (int j = 0; j < WNT; j++) bfr[j] = *(const bf16x8*)&Bs[(wn + j * 16 + l15) * 32 + quad * 8];
#pragma unroll
    for (int i = 0; i < WMT; i++)
#pragma unroll
      for (int j = 0; j < WNT; j++)
        acc[i][j] = __builtin_amdgcn_mfma_f32_16x16x32_bf16(af[i], bfr[j], acc[i][j], 0, 0, 0);
    __syncthreads();
  }

  float sb = 0.f;
  if (BIASM == 2) sb = bias[0] + bias[1];
#pragma unroll
  for (int i = 0; i < WMT; i++)
#pragma unroll
    for (int j = 0; j < WNT; j++) {
      int col = col0 + wn + j * 16 + l15;
      float bv = (BIASM == 1) ? bias[col] : sb;
#pragma unroll
      for (int r = 0; r < 4; r++) {
        int row = row0 + wm + i * 16 + (quad << 2) + r;
        float v = acc[i][j][r] + bv;
        if (ACT == 1) v = fmaxf(v, 0.f);
        if (ACT == 2) v = 0.5f * v * (1.f + erff(v * 0.70710678118654752f));
        long long ci = (long long)blockIdx.z * sC + (long long)row * ldc + col;
        if (SMODE & 1) Cf[ci] = v;
        if (SMODE & 2) Cb[ci] = __float2bfloat16(v);
      }
    }
}

// ================= MFMA attention (bf16 QKV) =================
// Block = (qtile 64, h, b); 4 waves; wave = 16-q-row strip.
// QKV: (4096, 768) bf16 packed [Q|K|V]. aw fp32 out; ctx bf16 (4096,256).
template<int BRANCH>
__global__ __launch_bounds__(256, 2)
void attn_mfma(const bf16* __restrict__ QKV, const int* __restrict__ mask,
               const float* __restrict__ extra, float* __restrict__ aw,
               bf16* __restrict__ ctx)
{
  const int qt = blockIdx.x, h = blockIdx.y, b = blockIdx.z;
  const int t = threadIdx.x, lane = t & 63, wave = t >> 6;
  const int l15 = lane & 15, quad = lane >> 4;
  __shared__ bf16x8 Vt[64][32];   // [kpos-block of 8][dep], 32 KB

  // ---- stage V transposed+blocked ----
  {
    const bf16* Vb = QKV + (long long)b * SS * 768 + 512 + h * 32;
    int dep = t & 31;
#pragma unroll
    for (int j8 = 0; j8 < 8; j8++) {
      int blk = (t >> 5) + (j8 << 3);
      union { bf16x8 v; bf16 hh[8]; } u;
#pragma unroll
      for (int i = 0; i < 8; i++)
        u.hh[i] = Vb[(long long)(blk * 8 + i) * 768 + dep];
      Vt[blk][dep] = u.v;
    }
  }

  const int q0 = qt * 64 + wave * 16;
  const bf16* Qb = QKV + ((long long)(b * SS + q0)) * 768 + h * 32;
  bf16x8 qfrag = *(const bf16x8*)(Qb + (long long)l15 * 768 + quad * 8);
  __syncthreads();

  const float scale_inv = 0.17677669529663688f; // 1/sqrt(32)
  const bf16* Kb = QKV + (long long)b * SS * 768 + 256 + h * 32;
  const float* Eb = extra + ((long long)b * SS + q0) * SS;
  float sreg[32][4];
  float rmax[4] = {-1e30f, -1e30f, -1e30f, -1e30f};
#pragma unroll
  for (int kc = 0; kc < 32; kc++) {
    int kpos = kc * 16 + l15;
    bf16x8 kfrag = *(const bf16x8*)(Kb + (long long)kpos * 768 + quad * 8);
    f32x4 a = __builtin_amdgcn_mfma_f32_16x16x32_bf16(qfrag, kfrag, f32x4{0.f,0.f,0.f,0.f}, 0, 0, 0);
    float mval = (float)mask[b * SS + kpos] * -1e9f;
#pragma unroll
    for (int r = 0; r < 4; r++) {
      float s = a[r];
      float ev = Eb[(long long)(quad * 4 + r) * SS + kpos];
      if (BRANCH == 1) {
        s = s * scale_inv + mval + ev;
      } else {
        float resc = 3.7182818284590452f / (1.f + __expf(1.f - ev));
        s = fmaxf(s, 0.f) * resc * scale_inv + mval;
      }
      sreg[kc][r] = s;
      rmax[r] = fmaxf(rmax[r], s);
    }
  }
#pragma unroll
  for (int r = 0; r < 4; r++) {
    float v = rmax[r];
    v = fmaxf(v, __shfl_xor(v, 1, 16));
    v = fmaxf(v, __shfl_xor(v, 2, 16));
    v = fmaxf(v, __shfl_xor(v, 4, 16));
    v = fmaxf(v, __shfl_xor(v, 8, 16));
    rmax[r] = v;
  }
  float rsum[4] = {0.f, 0.f, 0.f, 0.f};
#pragma unroll
  for (int kc = 0; kc < 32; kc++)
#pragma unroll
    for (int r = 0; r < 4; r++) {
      float e = __expf(sreg[kc][r] - rmax[r]);
      sreg[kc][r] = e;
      rsum[r] += e;
    }
#pragma unroll
  for (int r = 0; r < 4; r++) {
    float v = rsum[r];
    v += __shfl_xor(v, 1, 16);
    v += __shfl_xor(v, 2, 16);
    v += __shfl_xor(v, 4, 16);
    v += __shfl_xor(v, 8, 16);
    rsum[r] = 1.f / v;
  }
  float* awp = aw + (((long long)(b * NH + h) * SS + q0)) * SS;
#pragma unroll
  for (int kc = 0; kc < 32; kc++)
#pragma unroll
    for (int r = 0; r < 4; r++)
      awp[(long long)(quad * 4 + r) * SS + kc * 16 + l15] = sreg[kc][r] * rsum[r];

  asm volatile("s_waitcnt vmcnt(0)" ::: "memory");

  f32x4 oacc[2] = {};
#pragma unroll
  for (int kc2 = 0; kc2 < 16; kc2++) {
    bf16x8 afr = cvt8(awp + (long long)l15 * SS + kc2 * 32 + quad * 8);
#pragma unroll
    for (int n = 0; n < 2; n++) {
      bf16x8 bfr = Vt[kc2 * 4 + quad][n * 16 + l15];
      oacc[n] = __builtin_amdgcn_mfma_f32_16x16x32_bf16(afr, bfr, oacc[n], 0, 0, 0);
    }
  }
#pragma unroll
  for (int n = 0; n < 2; n++)
#pragma unroll
    for (int r = 0; r < 4; r++) {
      int q = q0 + quad * 4 + r;
      ctx[(long long)(b * SS + q) * DHm + h * 32 + n * 16 + l15] = __float2bfloat16(oacc[n][r]);
    }
}

// ================= pack_all: weight transposes fp32(K,N)->bf16(N,K), x->bf16, biases =================
__device__ __forceinline__ void tr_tile(const float* __restrict__ src, bf16* __restrict__ dst,
                                        int K, int N, int tile) {
  __shared__ float tl[32][33];
  int tilesN = N >> 5;
  int tk = tile / tilesN, tn = tile % tilesN;
  int c = threadIdx.x & 31, r0 = threadIdx.x >> 5;
#pragma unroll
  for (int i = 0; i < 4; i++) {
    int r = r0 + i * 8;
    tl[r][c] = src[(long long)(tk * 32 + r) * N + tn * 32 + c];
  }
  __syncthreads();
#pragma unroll
  for (int i = 0; i < 4; i++) {
    int r = r0 + i * 8;
    dst[(long long)(tn * 32 + r) * K + tk * 32 + c] = __float2bfloat16(tl[c][r]);
  }
}

__global__ __launch_bounds__(256)
void pack_all(const float* wq1, const float* wk1, const float* wv1,
              const float* wq2, const float* wk2, const float* wv2,
              const float* wo1, const float* wo2,
              const float* vnet_w, const float* qnet_w,
              const float* ffn_w1, const float* ffn_w2,
              const float* bq1, const float* bk1, const float* bv1,
              const float* bq2, const float* bk2, const float* bv2,
              const float* x,
              bf16* WB1, bf16* WB2, bf16* woT1, bf16* woT2,
              bf16* vnetT, bf16* qnetT, bf16* f1T, bf16* f2T,
              float* BB1v, float* BB2v, bf16* xb)
{
  int blk = blockIdx.x;
  if (blk < 64)        { tr_tile(wq1, WB1,            256, 256, blk); return; }
  if (blk < 128)       { tr_tile(wk1, WB1 + 256*256,  256, 256, blk-64); return; }
  if (blk < 192)       { tr_tile(wv1, WB1 + 512*256,  256, 256, blk-128); return; }
  if (blk < 256)       { tr_tile(wq2, WB2,            256, 256, blk-192); return; }
  if (blk < 320)       { tr_tile(wk2, WB2 + 256*256,  256, 256, blk-256); return; }
  if (blk < 384)       { tr_tile(wv2, WB2 + 512*256,  256, 256, blk-320); return; }
  if (blk < 448)       { tr_tile(wo1, woT1,           256, 256, blk-384); return; }
  if (blk < 512)       { tr_tile(wo2, woT2,           256, 256, blk-448); return; }
  if (blk < 640)       { tr_tile(vnet_w, vnetT,       256, 512, blk-512); return; }
  if (blk < 768)       { tr_tile(qnet_w, qnetT,       256, 512, blk-640); return; }
  if (blk < 1792)      { tr_tile(ffn_w1, f1T,         512, 2048, blk-768); return; }
  if (blk < 2816)      { tr_tile(ffn_w2, f2T,         2048, 512, blk-1792); return; }
  if (blk < 3840) {
    long long i0 = (long long)(blk - 2816) * 2048 + threadIdx.x * 8;
    *(bf16x8*)(xb + i0) = cvt8(x + i0);
    return;
  }
  {
    int b = blk - 3840; // 0..5
    const float* src = b==0?bq1 : b==1?bk1 : b==2?bv1 : b==3?bq2 : b==4?bk2 : bv2;
    float* dst = (b < 3 ? BB1v : BB2v) + (b % 3) * 256;
    dst[threadIdx.x] = src[threadIdx.x];
  }
}

// ---------------- per-batch bf16 transpose Qn (512x512) -> QnT ----------------
__global__ __launch_bounds__(256)
void tr_qn(const bf16* __restrict__ Qn, bf16* __restrict__ QnT)
{
  int b = blockIdx.z, tk = blockIdx.y, tn = blockIdx.x;
  __shared__ bf16 tl[32][33];
  int c = threadIdx.x & 31, r0 = threadIdx.x >> 5;
  const bf16* src = Qn + (long long)b * 512 * 512;
  bf16* dst = QnT + (long long)b * 512 * 512;
#pragma unroll
  for (int i = 0; i < 4; i++) { int r = r0 + i * 8; tl[r][c] = src[(tk * 32 + r) * 512 + tn * 32 + c]; }
  __syncthreads();
#pragma unroll
  for (int i = 0; i < 4; i++) { int r = r0 + i * 8; dst[(tn * 32 + r) * 512 + tk * 32 + c] = tl[c][r]; }
}

// ---------------- vh = v_ * (h_mat[0,:]+h_mat[1,:]) (bf16 in/out) ----------------
__global__ __launch_bounds__(256)
void vh_kernel(const bf16* __restrict__ v_, const float* __restrict__ hmat,
               bf16* __restrict__ vh, int n)
{
  int i = blockIdx.x * 256 + threadIdx.x;
  if (i < n) {
    int c = i & (DD - 1);
    vh[i] = __float2bfloat16(__bfloat162float(v_[i]) * (hmat[c] + hmat[DD + c]));
  }
}

// ---------------- BN(eval) + gate + residual + LN1 (dual-store) ----------------
__global__ __launch_bounds__(256)
void bn_gate_ln1_kernel(const float* __restrict__ x, const bf16* __restrict__ vbuf,
                        const float* __restrict__ T, const float* __restrict__ xl,
                        const float* __restrict__ xg,
                        const float* __restrict__ bng, const float* __restrict__ bnb,
                        const float* __restrict__ bnm, const float* __restrict__ bnv,
                        const float* __restrict__ lng, const float* __restrict__ lnb,
                        float* __restrict__ out1, bf16* __restrict__ out1b)
{
  const int row = blockIdx.x;
  const int t = threadIdx.x;
  __shared__ float red[256];
  float val[2];
#pragma unroll
  for (int i = 0; i < 2; i++) {
    int c = t + i * 256;
    long long idx = (long long)row * DD + c;
    float lg = __bfloat162float(vbuf[idx]) * T[idx];
    float bn = (lg - bnm[c]) / sqrtf(bnv[c] + 1e-3f) * bng[c] + bnb[c];
    float gate = (c < DHm) ? xl[(long long)row * DHm + c] : xg[(long long)row * DHm + (c - DHm)];
    val[i] = x[idx] + bn * gate;
  }
  red[t] = val[0] + val[1];
  __syncthreads();
  for (int o = 128; o > 0; o >>= 1) { if (t < o) red[t] += red[t + o]; __syncthreads(); }
  float mu = red[0] * (1.f / 512.f);
  __syncthreads();
  float d0 = val[0] - mu, d1 = val[1] - mu;
  red[t] = d0 * d0 + d1 * d1;
  __syncthreads();
  for (int o = 128; o > 0; o >>= 1) { if (t < o) red[t] += red[t + o]; __syncthreads(); }
  float inv = 1.f / sqrtf(red[0] * (1.f / 512.f) + 1e-6f);
  float o0 = d0 * inv * lng[t] + lnb[t];
  float o1 = d1 * inv * lng[t + 256] + lnb[t + 256];
  out1[(long long)row * DD + t] = o0;
  out1[(long long)row * DD + t + 256] = o1;
  out1b[(long long)row * DD + t] = __float2bfloat16(o0);
  out1b[(long long)row * DD + t + 256] = __float2bfloat16(o1);
}

// ---------------- residual + LN2 -> out ----------------
__global__ __launch_bounds__(256)
void ln2_kernel(const float* __restrict__ a, const float* __restrict__ b2,
                const float* __restrict__ g, const float* __restrict__ bta,
                float* __restrict__ out)
{
  const int row = blockIdx.x;
  const int t = threadIdx.x;
  __shared__ float red[256];
  float v0 = a[(long long)row * DD + t]       + b2[(long long)row * DD + t];
  float v1 = a[(long long)row * DD + t + 256] + b2[(long long)row * DD + t + 256];
  red[t] = v0 + v1;
  __syncthreads();
  for (int o = 128; o > 0; o >>= 1) { if (t < o) red[t] += red[t + o]; __syncthreads(); }
  float mu = red[0] * (1.f / 512.f);
  __syncthreads();
  float d0 = v0 - mu, d1 = v1 - mu;
  red[t] = d0 * d0 + d1 * d1;
  __syncthreads();
  for (int o = 128; o > 0; o >>= 1) { if (t < o) red[t] += red[t + o]; __syncthreads(); }
  float inv = 1.f / sqrtf(red[0] * (1.f / 512.f) + 1e-6f);
  out[(long long)row * DD + t]       = d0 * inv * g[t]       + bta[t];
  out[(long long)row * DD + t + 256] = d1 * inv * g[t + 256] + bta[t + 256];
}

extern "C" void kernel_launch(void* const* d_in, const int* in_sizes, int n_in,
                              void* d_out, int out_size, void* d_ws, size_t ws_size,
                              hipStream_t stream) {
  const float* x      = (const float*)d_in[0];
  const float* adjoin = (const float*)d_in[1];
  const float* dist   = (const float*)d_in[2];
  const float* wq1=(const float*)d_in[3],  *bq1=(const float*)d_in[4];
  const float* wk1=(const float*)d_in[5],  *bk1=(const float*)d_in[6];
  const float* wv1=(const float*)d_in[7],  *bv1=(const float*)d_in[8];
  const float* wo1=(const float*)d_in[9],  *bo1=(const float*)d_in[10];
  const float* wq2=(const float*)d_in[11], *bq2=(const float*)d_in[12];
  const float* wk2=(const float*)d_in[13], *bk2=(const float*)d_in[14];
  const float* wv2=(const float*)d_in[15], *bv2=(const float*)d_in[16];
  const float* wo2=(const float*)d_in[17], *bo2=(const float*)d_in[18];
  const float* vnet_w=(const float*)d_in[19], *vnet_b=(const float*)d_in[20];
  const float* qnet_w=(const float*)d_in[21], *qnet_b=(const float*)d_in[22];
  const float* h_mat=(const float*)d_in[23], *h_bias=(const float*)d_in[24];
  const float* bn_g=(const float*)d_in[25], *bn_b=(const float*)d_in[26];
  const float* bn_m=(const float*)d_in[27], *bn_v=(const float*)d_in[28];
  const float* ln1_g=(const float*)d_in[29], *ln1_b=(const float*)d_in[30];
  const float* ln2_g=(const float*)d_in[31], *ln2_b=(const float*)d_in[32];
  const float* ffn_w1=(const float*)d_in[33], *ffn_b1=(const float*)d_in[34];
  const float* ffn_w2=(const float*)d_in[35], *ffn_b2=(const float*)d_in[36];
  const int* mask = (const int*)d_in[37];

  // ---- workspace layout (bytes) ----
  char* base = (char*)d_ws;
  size_t off = 0;
  auto alloc = [&](size_t bytes) { char* p = base + off; off += (bytes + 255) & ~(size_t)255; return p; };
  bf16*  xb    = (bf16*) alloc(4096LL*512*2);
  bf16*  WB1   = (bf16*) alloc(768*256*2);
  bf16*  WB2   = (bf16*) alloc(768*256*2);
  float* BB1v  = (float*)alloc(768*4);
  float* BB2v  = (float*)alloc(768*4);
  bf16*  woT1  = (bf16*) alloc(256*256*2);
  bf16*  woT2  = (bf16*) alloc(256*256*2);
  bf16*  vnetT = (bf16*) alloc(512*256*2);
  bf16*  qnetT = (bf16*) alloc(512*256*2);
  bf16*  f1T   = (bf16*) alloc(2048*512*2);
  bf16*  f2T   = (bf16*) alloc(512*2048*2);
  bf16*  QKV1  = (bf16*) alloc(4096LL*768*2);
  bf16*  QKV2  = (bf16*) alloc(4096LL*768*2);
  bf16*  CTX   = (bf16*) alloc(4096LL*256*2);
  float* XL    = (float*)alloc(4096LL*256*4);
  float* XG    = (float*)alloc(4096LL*256*4);
  bf16*  XLb   = (bf16*) alloc(4096LL*256*2);
  bf16*  XGb   = (bf16*) alloc(4096LL*256*2);
  bf16*  Vn    = (bf16*) alloc(4096LL*512*2);
  bf16*  Qn    = (bf16*) alloc(4096LL*512*2);
  bf16*  QnT   = (bf16*) alloc(4096LL*512*2);
  bf16*  VH    = (bf16*) alloc(4096LL*512*2);
  bf16*  G     = (bf16*) alloc(8LL*512*512*2);
  float* T     = (float*)alloc(4096LL*512*4);
  float* OUT1  = (float*)alloc(4096LL*512*4);
  bf16*  OUT1b = (bf16*) alloc(4096LL*512*2);
  bf16*  H     = (bf16*) alloc(4096LL*2048*2);
  float* FFNO  = (float*)alloc(4096LL*512*4);

  float* out2 = (float*)d_out;
  float* awl  = out2 + 2097152LL;
  float* awg  = awl + 16777216LL;

  const int MR = BB * SS; // 4096
  const long long GST = (long long)SS * SS;

  // ---- pack everything to bf16 ----
  pack_all<<<dim3(3846), 256, 0, stream>>>(
      wq1, wk1, wv1, wq2, wk2, wv2, wo1, wo2, vnet_w, qnet_w, ffn_w1, ffn_w2,
      bq1, bk1, bv1, bq2, bk2, bv2, x,
      WB1, WB2, woT1, woT2, vnetT, qnetT, f1T, f2T, BB1v, BB2v, xb);

  // ---- QKV projections (big tiles) ----
  gemm2<128,128,2,1,0><<<dim3(6, 32, 1), 256, 0, stream>>>(
      xb,       WB1, BB1v, nullptr, QKV1, 256, 512, 256, 768, 0, 0, 0);
  gemm2<128,128,2,1,0><<<dim3(6, 32, 1), 256, 0, stream>>>(
      xb + 256, WB2, BB2v, nullptr, QKV2, 256, 512, 256, 768, 0, 0, 0);

  // ---- attention ----
  attn_mfma<1><<<dim3(8, NH, BB), 256, 0, stream>>>(QKV1, mask, adjoin, awl, CTX);
  gemm2<64,64,3,1,0><<<dim3(4, 64, 1), 256, 0, stream>>>(
      CTX, woT1, bo1, XL, XLb, 256, 256, 256, 256, 0, 0, 0);
  attn_mfma<2><<<dim3(8, NH, BB), 256, 0, stream>>>(QKV2, mask, dist, awg, CTX);
  gemm2<64,64,3,1,0><<<dim3(4, 64, 1), 256, 0, stream>>>(
      CTX, woT2, bo2, XG, XGb, 256, 256, 256, 256, 0, 0, 0);

  // ---- BAN ----
  gemm2<64,64,2,1,1><<<dim3(8, 64, 1), 256, 0, stream>>>(
      XLb, vnetT, vnet_b, nullptr, Vn, 256, 256, 256, 512, 0, 0, 0);
  gemm2<64,64,2,1,1><<<dim3(8, 64, 1), 256, 0, stream>>>(
      XGb, qnetT, qnet_b, nullptr, Qn, 256, 256, 256, 512, 0, 0, 0);
  vh_kernel<<<dim3((MR * DD) / 256), 256, 0, stream>>>(Vn, h_mat, VH, MR * DD);
  tr_qn<<<dim3(16, 16, BB), 256, 0, stream>>>(Qn, QnT);
  gemm2<64,64,2,2,0><<<dim3(8, 8, BB), 256, 0, stream>>>(
      VH, Qn, h_bias, nullptr, G, 512, 512, 512, 512, GST, GST, GST);
  gemm2<64,64,1,0,0><<<dim3(8, 8, BB), 256, 0, stream>>>(
      G, QnT, nullptr, T, nullptr, 512, 512, 512, 512, GST, GST, GST);

  // ---- BN + gate + residual + LN1 ----
  bn_gate_ln1_kernel<<<dim3(MR), 256, 0, stream>>>(
      x, Vn, T, XL, XG, bn_g, bn_b, bn_m, bn_v, ln1_g, ln1_b, OUT1, OUT1b);

  // ---- FFN ----
  gemm2<128,128,2,1,2><<<dim3(16, 32, 1), 256, 0, stream>>>(
      OUT1b, f1T, ffn_b1, nullptr, H, 512, 512, 512, 2048, 0, 0, 0);
  gemm2<64,64,1,1,0><<<dim3(8, 64, 1), 256, 0, stream>>>(
      H, f2T, ffn_b2, FFNO, nullptr, 2048, 2048, 2048, 512, 0, 0, 0);

  // ---- residual + LN2 -> out ----
  ln2_kernel<<<dim3(MR), 256, 0, stream>>>(OUT1, FFNO, ln2_g, ln2_b, out2);
}